// Round 1
// baseline (2007.389 us; speedup 1.0000x reference)
//
#include <hip/hip_runtime.h>
#include <hip/hip_bf16.h>

namespace {

constexpr int B   = 1024;
constexpr int PEP = 15;
constexpr int MHCN = 44;
constexpr int S   = 59;    // sequence
constexpr int V   = 21;    // vocab / model dim
constexpr int C   = 3200;  // conv channels
constexpr int KW  = 9;     // depthwise kernel
constexpr int H   = 9;     // heads
constexpr int NH  = 800;
constexpr int SV  = S * V;   // 1239
constexpr int HD  = H * V;   // 189
constexpr float EPSF = 1e-5f;

__device__ __forceinline__ float sigm(float x) { return 1.f / (1.f + __expf(-x)); }

// ---------------- K1: concat pep+mhc -> X0 [B,59,21] ----------------
__global__ void k_concat(const float* __restrict__ pep, const float* __restrict__ mhc,
                         float* __restrict__ X0) {
  int i = blockIdx.x * 256 + threadIdx.x;
  if (i >= B * SV) return;
  int b = i / SV;
  int r = i - b * SV;
  int l = r / V;
  int v = r - l * V;
  X0[i] = (l < PEP) ? pep[(b * PEP + l) * V + v] : mhc[(b * MHCN + (l - PEP)) * V + v];
}

// ---------------- K2: fused conv module + residual + LN -> X1 ----------------
// One block per batch element. Channels processed in chunks of CH=64 through LDS.
// Down-projection accumulated in registers (each thread owns a 2x3 (l,v) tile).
constexpr int CH = 64;
constexpr int GSTR = 69;  // glu row stride (59 interior + 4 zero pad each side, odd stride)

__global__ __launch_bounds__(256) void k_conv(
    const float* __restrict__ X0, const float* __restrict__ W1, const float* __restrict__ b1,
    const float* __restrict__ Wd, const float* __restrict__ bd,
    const float* __restrict__ bn_g, const float* __restrict__ bn_b,
    const float* __restrict__ bn_m, const float* __restrict__ bn_v,
    const float* __restrict__ W2, const float* __restrict__ b2,
    const float* __restrict__ lng, const float* __restrict__ lnb,
    float* __restrict__ X1) {
  __shared__ __align__(16) float Xs[S * 24];      // padded rows (only v<21 used)
  __shared__ float glu[CH * GSTR];                // GLU output, zero-padded halo for conv
  __shared__ float sb[CH * 59 + 1];               // post-silu; +1 pad for harmless OOB read
  __shared__ float yacc[SV];
  const int t = threadIdx.x;
  const int b = blockIdx.x;

  for (int i = t; i < SV; i += 256) {
    int l = i / V, v = i - l * V;
    Xs[l * 24 + v] = X0[b * SV + i];
  }
  for (int i = t; i < CH * GSTR; i += 256) glu[i] = 0.f;  // halo stays zero forever
  __syncthreads();

  const int c  = t & 63;   // P1/P2: channel within chunk
  const int l0 = t >> 6;   // P1/P2: starting position (stride 4)
  // P3 tile ownership: 1239 outputs as 30 (l-pairs) x 7 (v-triples) = 210 tiles
  const int lp  = t / 7;
  const int vt  = t - lp * 7;
  const int l0p = 2 * lp;
  const int v0  = 3 * vt;
  float a00 = 0, a01 = 0, a02 = 0, a10 = 0, a11 = 0, a12 = 0;

  for (int cb = 0; cb < C; cb += CH) {
    const int cg = cb + c;
    // ---- P1: GLU  a*sigmoid(g), weights in registers ----
    {
      float wa[V], wg[V];
#pragma unroll
      for (int v = 0; v < V; ++v) {
        wa[v] = W1[cg * V + v];
        wg[v] = W1[(cg + C) * V + v];
      }
      const float ba = b1[cg], bg = b1[cg + C];
      for (int l = l0; l < S; l += 4) {
        float a = ba, g = bg;
#pragma unroll
        for (int v = 0; v < V; ++v) {
          float x = Xs[l * 24 + v];
          a = fmaf(x, wa[v], a);
          g = fmaf(x, wg[v], g);
        }
        glu[c * GSTR + 4 + l] = a * sigm(g);
      }
    }
    __syncthreads();
    // ---- P2: depthwise conv (K=9, pad 4) + BN(inference) + SiLU ----
    {
      float wd[KW];
#pragma unroll
      for (int k = 0; k < KW; ++k) wd[k] = Wd[cg * KW + k];
      const float bdd = bd[cg];
      const float sc = bn_g[cg] * rsqrtf(bn_v[cg] + EPSF);
      const float sh = bn_b[cg] - bn_m[cg] * sc;
      for (int l = l0; l < S; l += 4) {
        float acc = bdd;
#pragma unroll
        for (int k = 0; k < KW; ++k) acc = fmaf(glu[c * GSTR + l + k], wd[k], acc);
        acc = fmaf(acc, sc, sh);
        sb[c * 59 + l] = acc * sigm(acc);
      }
    }
    __syncthreads();
    // ---- P3: down-projection partial sums into registers ----
    if (t < 210) {
      const float* w2a = W2 + v0 * C + cb;
      const float* w2b = w2a + C;
      const float* w2c = w2b + C;
#pragma unroll 4
      for (int c2 = 0; c2 < CH; ++c2) {
        const float s0 = sb[c2 * 59 + l0p];
        const float s1 = sb[c2 * 59 + l0p + 1];  // lp==29: pad read, result discarded
        const float w0 = w2a[c2], w1 = w2b[c2], w2v = w2c[c2];
        a00 = fmaf(s0, w0, a00); a01 = fmaf(s0, w1, a01); a02 = fmaf(s0, w2v, a02);
        a10 = fmaf(s1, w0, a10); a11 = fmaf(s1, w1, a11); a12 = fmaf(s1, w2v, a12);
      }
    }
    __syncthreads();  // protects sb (P2 writes) and glu (P1 writes) of next chunk
  }

  if (t < 210) {
    yacc[l0p * V + v0]     = a00;
    yacc[l0p * V + v0 + 1] = a01;
    yacc[l0p * V + v0 + 2] = a02;
    if (l0p + 1 < S) {
      yacc[(l0p + 1) * V + v0]     = a10;
      yacc[(l0p + 1) * V + v0 + 1] = a11;
      yacc[(l0p + 1) * V + v0 + 2] = a12;
    }
  }
  __syncthreads();
  // ---- residual + b2 + LayerNorm over V ----
  if (t < S) {
    float z[V];
    float m = 0;
#pragma unroll
    for (int v = 0; v < V; ++v) {
      z[v] = X0[b * SV + t * V + v] + yacc[t * V + v] + b2[v];
      m += z[v];
    }
    m *= (1.f / V);
    float var = 0;
#pragma unroll
    for (int v = 0; v < V; ++v) {
      float d = z[v] - m;
      var = fmaf(d, d, var);
    }
    const float inv = rsqrtf(var * (1.f / V) + EPSF);
#pragma unroll
    for (int v = 0; v < V; ++v)
      X1[b * SV + t * V + v] = (z[v] - m) * inv * lng[v] + lnb[v];
  }
}

// ---------------- K3: per-(b,h) attention, qkv fused -> O [B,59,189] ----------------
__global__ __launch_bounds__(64) void k_attn(
    const float* __restrict__ X1, const float* __restrict__ Wq, const float* __restrict__ Wk,
    const float* __restrict__ Wv, float* __restrict__ O) {
  __shared__ float Xs[SV], qs[SV], ks[SV], vs[SV];
  __shared__ float wqs[V * V], wks[V * V], wvs[V * V];
  __shared__ float ss[S * 61];  // score rows, odd stride
  const int t = threadIdx.x;
  const int bh = blockIdx.x;
  const int b = bh / H;
  const int h = bh - b * H;

  for (int i = t; i < SV; i += 64) Xs[i] = X1[b * SV + i];
  for (int i = t; i < V * V; i += 64) {
    int vv = i / V, d = i - vv * V;
    wqs[i] = Wq[vv * HD + h * V + d];
    wks[i] = Wk[vv * HD + h * V + d];
    wvs[i] = Wv[vv * HD + h * V + d];
  }
  __syncthreads();
  for (int i = t; i < SV; i += 64) {
    int l = i / V, d = i - l * V;
    float q = 0, k = 0, vv = 0;
#pragma unroll
    for (int u = 0; u < V; ++u) {
      float x = Xs[l * V + u];
      q  = fmaf(x, wqs[u * V + d], q);
      k  = fmaf(x, wks[u * V + d], k);
      vv = fmaf(x, wvs[u * V + d], vv);
    }
    qs[i] = q; ks[i] = k; vs[i] = vv;
  }
  __syncthreads();
  if (t < S) {
    const float rs = 0.21821789023599236f;  // 1/sqrt(21)
    float qr[V];
#pragma unroll
    for (int d = 0; d < V; ++d) qr[d] = qs[t * V + d];
    float mx = -1e30f;
    for (int j = 0; j < S; ++j) {
      float acc = 0;
#pragma unroll
      for (int d = 0; d < V; ++d) acc = fmaf(qr[d], ks[j * V + d], acc);
      acc *= rs;
      ss[t * 61 + j] = acc;
      mx = fmaxf(mx, acc);
    }
    float sum = 0;
    for (int j = 0; j < S; ++j) {
      float e = __expf(ss[t * 61 + j] - mx);
      ss[t * 61 + j] = e;
      sum += e;
    }
    const float inv = 1.f / sum;
    float o[V];
#pragma unroll
    for (int d = 0; d < V; ++d) o[d] = 0.f;
    for (int j = 0; j < S; ++j) {
      float p = ss[t * 61 + j];
#pragma unroll
      for (int d = 0; d < V; ++d) o[d] = fmaf(p, vs[j * V + d], o[d]);
    }
    float* op = O + (size_t)(b * S + t) * HD + h * V;
#pragma unroll
    for (int d = 0; d < V; ++d) op[d] = o[d] * inv;
  }
}

// ---------------- K4: O @ Wo + residual + LN -> X2 ----------------
__global__ __launch_bounds__(128) void k_wo(
    const float* __restrict__ O, const float* __restrict__ Wo, const float* __restrict__ X1,
    const float* __restrict__ lng, const float* __restrict__ lnb, float* __restrict__ X2) {
  __shared__ float Ws[HD * V];
  __shared__ float yo[SV];
  const int t = threadIdx.x;
  const int b = blockIdx.x;
  for (int i = t; i < HD * V; i += 128) Ws[i] = Wo[i];
  __syncthreads();
  for (int i = t; i < SV; i += 128) {
    int l = i / V, v = i - l * V;
    const float* orow = O + (size_t)(b * S + l) * HD;
    float acc = 0;
#pragma unroll 9
    for (int m = 0; m < HD; ++m) acc = fmaf(orow[m], Ws[m * V + v], acc);
    yo[i] = acc;
  }
  __syncthreads();
  if (t < S) {
    float z[V];
    float m = 0;
#pragma unroll
    for (int v = 0; v < V; ++v) {
      z[v] = X1[b * SV + t * V + v] + yo[t * V + v];
      m += z[v];
    }
    m *= (1.f / V);
    float var = 0;
#pragma unroll
    for (int v = 0; v < V; ++v) {
      float d = z[v] - m;
      var = fmaf(d, d, var);
    }
    const float inv = rsqrtf(var * (1.f / V) + EPSF);
#pragma unroll
    for (int v = 0; v < V; ++v)
      X2[b * SV + t * V + v] = (z[v] - m) * inv * lng[v] + lnb[v];
  }
}

// ---------------- K5: head GEMM [B,1239]@[1239,800] + bias + silu + BN -> Hb ----------------
constexpr int BT = 8;    // batch rows per block
constexpr int NT = 200;  // output cols per block
__global__ __launch_bounds__(256) void k_f1(
    const float* __restrict__ X2, const float* __restrict__ Wf1, const float* __restrict__ bf1,
    const float* __restrict__ g2, const float* __restrict__ bb2, const float* __restrict__ m2,
    const float* __restrict__ v2, float* __restrict__ Hb) {
  __shared__ __align__(16) float Xs[BT * 1240];
  const int t = threadIdx.x;
  const int bbase = blockIdx.x * BT;
  const int nbase = blockIdx.y * NT;
  for (int i = t; i < BT * SV; i += 256) {
    int r = i / SV, f = i - r * SV;
    Xs[r * 1240 + f] = X2[(size_t)(bbase + r) * SV + f];
  }
  __syncthreads();
  if (t < NT) {
    const int n = nbase + t;
    float acc[BT];
#pragma unroll
    for (int r = 0; r < BT; ++r) acc[r] = 0.f;
    int f = 0;
    for (; f + 3 < SV; f += 4) {
      const float w0 = Wf1[(size_t)f * NH + n];
      const float w1 = Wf1[(size_t)(f + 1) * NH + n];
      const float w2 = Wf1[(size_t)(f + 2) * NH + n];
      const float w3 = Wf1[(size_t)(f + 3) * NH + n];
#pragma unroll
      for (int r = 0; r < BT; ++r) {
        const float4 x = *reinterpret_cast<const float4*>(&Xs[r * 1240 + f]);
        acc[r] = fmaf(x.x, w0, acc[r]);
        acc[r] = fmaf(x.y, w1, acc[r]);
        acc[r] = fmaf(x.z, w2, acc[r]);
        acc[r] = fmaf(x.w, w3, acc[r]);
      }
    }
    for (; f < SV; ++f) {
      const float w0 = Wf1[(size_t)f * NH + n];
#pragma unroll
      for (int r = 0; r < BT; ++r) acc[r] = fmaf(Xs[r * 1240 + f], w0, acc[r]);
    }
    const float sc = g2[n] * rsqrtf(v2[n] + EPSF);
    const float sh = bb2[n] - m2[n] * sc;
    const float bias = bf1[n];
#pragma unroll
    for (int r = 0; r < BT; ++r) {
      float hh = acc[r] + bias;
      hh = hh * sigm(hh);            // silu
      hh = fmaf(hh, sc, sh);         // BN2 (inference)
      Hb[(size_t)(bbase + r) * NH + n] = hh;
    }
  }
}

// ---------------- K6: relu(Hb@Wf2+bf2) @ Wf3 + bf3 -> out [B,2] ----------------
__global__ __launch_bounds__(64) void k_f23(
    const float* __restrict__ Hb, const float* __restrict__ Wf2, const float* __restrict__ bf2,
    const float* __restrict__ Wf3, const float* __restrict__ bf3, float* __restrict__ out) {
  __shared__ __align__(16) float hs[NH];
  const int t = threadIdx.x;
  const int b = blockIdx.x;
  for (int i = t; i < NH; i += 64) hs[i] = Hb[(size_t)b * NH + i];
  __syncthreads();
  float acc = bf2[t];
  for (int n = 0; n < NH; n += 4) {
    const float4 hv = *reinterpret_cast<const float4*>(&hs[n]);
    acc = fmaf(hv.x, Wf2[n * 64 + t], acc);
    acc = fmaf(hv.y, Wf2[(n + 1) * 64 + t], acc);
    acc = fmaf(hv.z, Wf2[(n + 2) * 64 + t], acc);
    acc = fmaf(hv.w, Wf2[(n + 3) * 64 + t], acc);
  }
  const float mid = fmaxf(acc, 0.f);
  float p0 = mid * Wf3[t * 2 + 0];
  float p1 = mid * Wf3[t * 2 + 1];
#pragma unroll
  for (int off = 32; off > 0; off >>= 1) {
    p0 += __shfl_down(p0, off);
    p1 += __shfl_down(p1, off);
  }
  if (t == 0) {
    out[b * 2 + 0] = p0 + bf3[0];
    out[b * 2 + 1] = p1 + bf3[1];
  }
}

}  // namespace

extern "C" void kernel_launch(void* const* d_in, const int* in_sizes, int n_in,
                              void* d_out, int out_size, void* d_ws, size_t ws_size,
                              hipStream_t stream) {
  const float* pep   = (const float*)d_in[0];
  const float* mhc   = (const float*)d_in[1];
  const float* W1    = (const float*)d_in[2];
  const float* b1    = (const float*)d_in[3];
  const float* Wd    = (const float*)d_in[4];
  const float* bd    = (const float*)d_in[5];
  const float* bn1_g = (const float*)d_in[6];
  const float* bn1_b = (const float*)d_in[7];
  const float* bn1_m = (const float*)d_in[8];
  const float* bn1_v = (const float*)d_in[9];
  const float* W2    = (const float*)d_in[10];
  const float* b2    = (const float*)d_in[11];
  const float* ln_g  = (const float*)d_in[12];
  const float* ln_b  = (const float*)d_in[13];
  const float* Wq    = (const float*)d_in[14];
  const float* Wk    = (const float*)d_in[15];
  const float* Wv    = (const float*)d_in[16];
  const float* Wo    = (const float*)d_in[17];
  const float* Wf1   = (const float*)d_in[18];
  const float* bf1   = (const float*)d_in[19];
  const float* bn2_g = (const float*)d_in[20];
  const float* bn2_b = (const float*)d_in[21];
  const float* bn2_m = (const float*)d_in[22];
  const float* bn2_v = (const float*)d_in[23];
  const float* Wf2   = (const float*)d_in[24];
  const float* bf2   = (const float*)d_in[25];
  const float* Wf3   = (const float*)d_in[26];
  const float* bf3   = (const float*)d_in[27];
  float* out = (float*)d_out;

  float* ws = (float*)d_ws;
  float* X0 = ws;                          // [B,59,21]
  float* X1 = X0 + (size_t)B * SV;         // [B,59,21]
  float* X2 = X1 + (size_t)B * SV;         // [B,59,21]
  float* O  = X2 + (size_t)B * SV;         // [B,59,189]
  float* Hb = O + (size_t)B * S * HD;      // [B,800]

  k_concat<<<(B * SV + 255) / 256, 256, 0, stream>>>(pep, mhc, X0);
  k_conv<<<B, 256, 0, stream>>>(X0, W1, b1, Wd, bd, bn1_g, bn1_b, bn1_m, bn1_v,
                                W2, b2, ln_g, ln_b, X1);
  k_attn<<<B * H, 64, 0, stream>>>(X1, Wq, Wk, Wv, O);
  k_wo<<<B, 128, 0, stream>>>(O, Wo, X1, ln_g, ln_b, X2);
  dim3 g5(B / BT, NH / NT);
  k_f1<<<g5, 256, 0, stream>>>(X2, Wf1, bf1, bn2_g, bn2_b, bn2_m, bn2_v, Hb);
  k_f23<<<B, 64, 0, stream>>>(Hb, Wf2, bf2, Wf3, bf3, out);
}

// Round 2
// 1216.542 us; speedup vs baseline: 1.6501x; 1.6501x over previous
//
#include <hip/hip_runtime.h>
#include <hip/hip_bf16.h>

namespace {

constexpr int B   = 1024;
constexpr int PEP = 15;
constexpr int MHCN = 44;
constexpr int S   = 59;    // sequence
constexpr int V   = 21;    // vocab / model dim
constexpr int C   = 3200;  // conv channels
constexpr int KW  = 9;     // depthwise kernel
constexpr int H   = 9;     // heads
constexpr int NH  = 800;
constexpr int SV  = S * V;   // 1239
constexpr int HD  = H * V;   // 189
constexpr float EPSF = 1e-5f;

__device__ __forceinline__ float sigm(float x) { return 1.f / (1.f + __expf(-x)); }

// ---------------- K1: concat pep+mhc -> X0 [B,59,21] ----------------
__global__ void k_concat(const float* __restrict__ pep, const float* __restrict__ mhc,
                         float* __restrict__ X0) {
  int i = blockIdx.x * 256 + threadIdx.x;
  if (i >= B * SV) return;
  int b = i / SV;
  int r = i - b * SV;
  int l = r / V;
  int v = r - l * V;
  X0[i] = (l < PEP) ? pep[(b * PEP + l) * V + v] : mhc[(b * MHCN + (l - PEP)) * V + v];
}

// ---------------- K0: pack per-channel conv-module params ----------------
// Per-channel record (stride 88 floats = 352B, 16B aligned):
//   [0..20]  wa = W1[c]          (GLU 'a' projection row)
//   [24..44] wg = W1[c+C]        (GLU 'g' projection row)
//   [48..56] wd[9]               (depthwise taps)
//   [57] ba   [58] bg            (GLU biases)
//   [59] sc2  [60] sh2           (folded conv-bias + BN affine)
//   [64..84] w2t = W2[:, c]      (down-proj column, transposed)
constexpr int PKS = 88;
__global__ void k_pack(const float* __restrict__ W1, const float* __restrict__ b1,
                       const float* __restrict__ Wd, const float* __restrict__ bd,
                       const float* __restrict__ g, const float* __restrict__ bb,
                       const float* __restrict__ m, const float* __restrict__ vv,
                       const float* __restrict__ W2, float* __restrict__ pk) {
  int c = blockIdx.x * 64 + threadIdx.x;
  if (c >= C) return;
  float* p = pk + (size_t)c * PKS;
  for (int i = 0; i < V; ++i) p[i] = W1[c * V + i];
  for (int i = 0; i < V; ++i) p[24 + i] = W1[(c + C) * V + i];
  for (int k = 0; k < KW; ++k) p[48 + k] = Wd[c * KW + k];
  float sc = g[c] * rsqrtf(vv[c] + EPSF);
  p[57] = b1[c];
  p[58] = b1[c + C];
  p[59] = sc;
  p[60] = (bd[c] - m[c]) * sc + bb[c];
  for (int i = 0; i < V; ++i) p[64 + i] = W2[(size_t)i * C + c];
}

// ---------------- K2: fused conv module + residual + LN -> X1 ----------------
// One block per batch element, 4 waves. lane = sequence position, wave = channel.
// X row and down-proj accumulator live in registers for the whole kernel.
// Weights are wave-uniform (readfirstlane'd channel index -> scalar loads).
__global__ __launch_bounds__(256) void k_conv(
    const float* __restrict__ X0, const float* __restrict__ pack,
    const float* __restrict__ b2, const float* __restrict__ lng,
    const float* __restrict__ lnb, float* __restrict__ X1) {
  __shared__ float grow[4][72];        // per-wave depthwise exchange row (4-zero halo each side)
  __shared__ float part[4][64 * V];    // per-wave down-proj partials
  __shared__ float yfull[64 * V];      // reduced down-proj output
  const int t = threadIdx.x;
  const int b = blockIdx.x;
  const int lane = t & 63;
  const int w = __builtin_amdgcn_readfirstlane(t >> 6);

  // zero the halo rows once (interior is rewritten every channel)
  for (int i = t; i < 4 * 72; i += 256) (&grow[0][0])[i] = 0.f;

  // persistent registers: input row + output accumulator
  float x[V];
  {
    const int row = lane < S ? lane : S - 1;
    const float* xr = X0 + (size_t)b * SV + row * V;
#pragma unroll
    for (int v = 0; v < V; ++v) x[v] = xr[v];
  }
  float yac[V];
#pragma unroll
  for (int v = 0; v < V; ++v) yac[v] = 0.f;
  __syncthreads();  // grow halo visible to own wave (and keeps init tidy)

  const bool wr = lane < S;
  for (int i = 0; i < C / 4; ++i) {
    const int c = 4 * i + w;  // wave-uniform channel
    const float* p = pack + (size_t)c * PKS;
    // ---- GLU ----
    float a = p[57], g = p[58];
#pragma unroll
    for (int v = 0; v < V; ++v) a = fmaf(x[v], p[v], a);
#pragma unroll
    for (int v = 0; v < V; ++v) g = fmaf(x[v], p[24 + v], g);
    const float gl = a * sigm(g);
    if (wr) grow[w][4 + lane] = gl;  // wave-synchronous: same wave consumes below
    // ---- depthwise conv + BN + SiLU ----
    float acc = 0.f;
#pragma unroll
    for (int k = 0; k < KW; ++k) acc = fmaf(grow[w][lane + k], p[48 + k], acc);
    acc = fmaf(acc, p[59], p[60]);
    const float sbv = acc * sigm(acc);
    // ---- down-projection accumulate (registers) ----
#pragma unroll
    for (int v = 0; v < V; ++v) yac[v] = fmaf(sbv, p[64 + v], yac[v]);
  }

  // cross-wave reduction of down-proj partials
#pragma unroll
  for (int v = 0; v < V; ++v) part[w][lane * V + v] = yac[v];
  __syncthreads();
  for (int e = t; e < SV; e += 256)
    yfull[e] = part[0][e] + part[1][e] + part[2][e] + part[3][e];
  __syncthreads();

  // residual + b2 + LayerNorm over V (wave 0; x[] regs still hold the residual row)
  if (w == 0 && lane < S) {
    float z[V];
    float mn = 0.f;
#pragma unroll
    for (int v = 0; v < V; ++v) {
      z[v] = x[v] + yfull[lane * V + v] + b2[v];
      mn += z[v];
    }
    mn *= (1.f / V);
    float var = 0.f;
#pragma unroll
    for (int v = 0; v < V; ++v) {
      float d = z[v] - mn;
      var = fmaf(d, d, var);
    }
    const float inv = rsqrtf(var * (1.f / V) + EPSF);
#pragma unroll
    for (int v = 0; v < V; ++v)
      X1[(size_t)b * SV + lane * V + v] = (z[v] - mn) * inv * lng[v] + lnb[v];
  }
}

// ---------------- K3: per-(b,h) attention, qkv fused -> O [B,59,189] ----------------
__global__ __launch_bounds__(64) void k_attn(
    const float* __restrict__ X1, const float* __restrict__ Wq, const float* __restrict__ Wk,
    const float* __restrict__ Wv, float* __restrict__ O) {
  __shared__ float Xs[SV], qs[SV], ks[SV], vs[SV];
  __shared__ float wqs[V * V], wks[V * V], wvs[V * V];
  __shared__ float ss[S * 61];  // score rows, odd stride
  const int t = threadIdx.x;
  const int bh = blockIdx.x;
  const int b = bh / H;
  const int h = bh - b * H;

  for (int i = t; i < SV; i += 64) Xs[i] = X1[b * SV + i];
  for (int i = t; i < V * V; i += 64) {
    int vv = i / V, d = i - vv * V;
    wqs[i] = Wq[vv * HD + h * V + d];
    wks[i] = Wk[vv * HD + h * V + d];
    wvs[i] = Wv[vv * HD + h * V + d];
  }
  __syncthreads();
  for (int i = t; i < SV; i += 64) {
    int l = i / V, d = i - l * V;
    float q = 0, k = 0, vv = 0;
#pragma unroll
    for (int u = 0; u < V; ++u) {
      float x = Xs[l * V + u];
      q  = fmaf(x, wqs[u * V + d], q);
      k  = fmaf(x, wks[u * V + d], k);
      vv = fmaf(x, wvs[u * V + d], vv);
    }
    qs[i] = q; ks[i] = k; vs[i] = vv;
  }
  __syncthreads();
  if (t < S) {
    const float rs = 0.21821789023599236f;  // 1/sqrt(21)
    float qr[V];
#pragma unroll
    for (int d = 0; d < V; ++d) qr[d] = qs[t * V + d];
    float mx = -1e30f;
    for (int j = 0; j < S; ++j) {
      float acc = 0;
#pragma unroll
      for (int d = 0; d < V; ++d) acc = fmaf(qr[d], ks[j * V + d], acc);
      acc *= rs;
      ss[t * 61 + j] = acc;
      mx = fmaxf(mx, acc);
    }
    float sum = 0;
    for (int j = 0; j < S; ++j) {
      float e = __expf(ss[t * 61 + j] - mx);
      ss[t * 61 + j] = e;
      sum += e;
    }
    const float inv = 1.f / sum;
    float o[V];
#pragma unroll
    for (int d = 0; d < V; ++d) o[d] = 0.f;
    for (int j = 0; j < S; ++j) {
      float p = ss[t * 61 + j];
#pragma unroll
      for (int d = 0; d < V; ++d) o[d] = fmaf(p, vs[j * V + d], o[d]);
    }
    float* op = O + (size_t)(b * S + t) * HD + h * V;
#pragma unroll
    for (int d = 0; d < V; ++d) op[d] = o[d] * inv;
  }
}

// ---------------- K4: O @ Wo + residual + LN -> X2 ----------------
__global__ __launch_bounds__(128) void k_wo(
    const float* __restrict__ O, const float* __restrict__ Wo, const float* __restrict__ X1,
    const float* __restrict__ lng, const float* __restrict__ lnb, float* __restrict__ X2) {
  __shared__ float Ws[HD * V];
  __shared__ float yo[SV];
  const int t = threadIdx.x;
  const int b = blockIdx.x;
  for (int i = t; i < HD * V; i += 128) Ws[i] = Wo[i];
  __syncthreads();
  for (int i = t; i < SV; i += 128) {
    int l = i / V, v = i - l * V;
    const float* orow = O + (size_t)(b * S + l) * HD;
    float acc = 0;
#pragma unroll 9
    for (int m = 0; m < HD; ++m) acc = fmaf(orow[m], Ws[m * V + v], acc);
    yo[i] = acc;
  }
  __syncthreads();
  if (t < S) {
    float z[V];
    float m = 0;
#pragma unroll
    for (int v = 0; v < V; ++v) {
      z[v] = X1[b * SV + t * V + v] + yo[t * V + v];
      m += z[v];
    }
    m *= (1.f / V);
    float var = 0;
#pragma unroll
    for (int v = 0; v < V; ++v) {
      float d = z[v] - m;
      var = fmaf(d, d, var);
    }
    const float inv = rsqrtf(var * (1.f / V) + EPSF);
#pragma unroll
    for (int v = 0; v < V; ++v)
      X2[b * SV + t * V + v] = (z[v] - m) * inv * lng[v] + lnb[v];
  }
}

// ---------------- K5: head GEMM [B,1239]@[1239,800] + bias + silu + BN -> Hb ----------------
constexpr int BT = 8;    // batch rows per block
constexpr int NT = 200;  // output cols per block
__global__ __launch_bounds__(256) void k_f1(
    const float* __restrict__ X2, const float* __restrict__ Wf1, const float* __restrict__ bf1,
    const float* __restrict__ g2, const float* __restrict__ bb2, const float* __restrict__ m2,
    const float* __restrict__ v2, float* __restrict__ Hb) {
  __shared__ __align__(16) float Xs[BT * 1240];
  const int t = threadIdx.x;
  const int bbase = blockIdx.x * BT;
  const int nbase = blockIdx.y * NT;
  for (int i = t; i < BT * SV; i += 256) {
    int r = i / SV, f = i - r * SV;
    Xs[r * 1240 + f] = X2[(size_t)(bbase + r) * SV + f];
  }
  __syncthreads();
  if (t < NT) {
    const int n = nbase + t;
    float acc[BT];
#pragma unroll
    for (int r = 0; r < BT; ++r) acc[r] = 0.f;
    int f = 0;
    for (; f + 3 < SV; f += 4) {
      const float w0 = Wf1[(size_t)f * NH + n];
      const float w1 = Wf1[(size_t)(f + 1) * NH + n];
      const float w2 = Wf1[(size_t)(f + 2) * NH + n];
      const float w3 = Wf1[(size_t)(f + 3) * NH + n];
#pragma unroll
      for (int r = 0; r < BT; ++r) {
        const float4 x = *reinterpret_cast<const float4*>(&Xs[r * 1240 + f]);
        acc[r] = fmaf(x.x, w0, acc[r]);
        acc[r] = fmaf(x.y, w1, acc[r]);
        acc[r] = fmaf(x.z, w2, acc[r]);
        acc[r] = fmaf(x.w, w3, acc[r]);
      }
    }
    for (; f < SV; ++f) {
      const float w0 = Wf1[(size_t)f * NH + n];
#pragma unroll
      for (int r = 0; r < BT; ++r) acc[r] = fmaf(Xs[r * 1240 + f], w0, acc[r]);
    }
    const float sc = g2[n] * rsqrtf(v2[n] + EPSF);
    const float sh = bb2[n] - m2[n] * sc;
    const float bias = bf1[n];
#pragma unroll
    for (int r = 0; r < BT; ++r) {
      float hh = acc[r] + bias;
      hh = hh * sigm(hh);            // silu
      hh = fmaf(hh, sc, sh);         // BN2 (inference)
      Hb[(size_t)(bbase + r) * NH + n] = hh;
    }
  }
}

// ---------------- K6: relu(Hb@Wf2+bf2) @ Wf3 + bf3 -> out [B,2] ----------------
__global__ __launch_bounds__(64) void k_f23(
    const float* __restrict__ Hb, const float* __restrict__ Wf2, const float* __restrict__ bf2,
    const float* __restrict__ Wf3, const float* __restrict__ bf3, float* __restrict__ out) {
  __shared__ __align__(16) float hs[NH];
  const int t = threadIdx.x;
  const int b = blockIdx.x;
  for (int i = t; i < NH; i += 64) hs[i] = Hb[(size_t)b * NH + i];
  __syncthreads();
  float acc = bf2[t];
  for (int n = 0; n < NH; n += 4) {
    const float4 hv = *reinterpret_cast<const float4*>(&hs[n]);
    acc = fmaf(hv.x, Wf2[n * 64 + t], acc);
    acc = fmaf(hv.y, Wf2[(n + 1) * 64 + t], acc);
    acc = fmaf(hv.z, Wf2[(n + 2) * 64 + t], acc);
    acc = fmaf(hv.w, Wf2[(n + 3) * 64 + t], acc);
  }
  const float mid = fmaxf(acc, 0.f);
  float p0 = mid * Wf3[t * 2 + 0];
  float p1 = mid * Wf3[t * 2 + 1];
#pragma unroll
  for (int off = 32; off > 0; off >>= 1) {
    p0 += __shfl_down(p0, off);
    p1 += __shfl_down(p1, off);
  }
  if (t == 0) {
    out[b * 2 + 0] = p0 + bf3[0];
    out[b * 2 + 1] = p1 + bf3[1];
  }
}

}  // namespace

extern "C" void kernel_launch(void* const* d_in, const int* in_sizes, int n_in,
                              void* d_out, int out_size, void* d_ws, size_t ws_size,
                              hipStream_t stream) {
  const float* pep   = (const float*)d_in[0];
  const float* mhc   = (const float*)d_in[1];
  const float* W1    = (const float*)d_in[2];
  const float* b1    = (const float*)d_in[3];
  const float* Wd    = (const float*)d_in[4];
  const float* bd    = (const float*)d_in[5];
  const float* bn1_g = (const float*)d_in[6];
  const float* bn1_b = (const float*)d_in[7];
  const float* bn1_m = (const float*)d_in[8];
  const float* bn1_v = (const float*)d_in[9];
  const float* W2    = (const float*)d_in[10];
  const float* b2    = (const float*)d_in[11];
  const float* ln_g  = (const float*)d_in[12];
  const float* ln_b  = (const float*)d_in[13];
  const float* Wq    = (const float*)d_in[14];
  const float* Wk    = (const float*)d_in[15];
  const float* Wv    = (const float*)d_in[16];
  const float* Wo    = (const float*)d_in[17];
  const float* Wf1   = (const float*)d_in[18];
  const float* bf1   = (const float*)d_in[19];
  const float* bn2_g = (const float*)d_in[20];
  const float* bn2_b = (const float*)d_in[21];
  const float* bn2_m = (const float*)d_in[22];
  const float* bn2_v = (const float*)d_in[23];
  const float* Wf2   = (const float*)d_in[24];
  const float* bf2   = (const float*)d_in[25];
  const float* Wf3   = (const float*)d_in[26];
  const float* bf3   = (const float*)d_in[27];
  float* out = (float*)d_out;

  float* ws = (float*)d_ws;
  float* X0 = ws;                          // [B,59,21]
  float* X1 = X0 + (size_t)B * SV;         // [B,59,21]
  float* X2 = X1 + (size_t)B * SV;         // [B,59,21]
  float* O  = X2 + (size_t)B * SV;         // [B,59,189]
  float* Hb = O + (size_t)B * S * HD;      // [B,800]
  float* Pk = Hb + (size_t)B * NH;         // [C,88] packed conv params

  k_pack<<<(C + 63) / 64, 64, 0, stream>>>(W1, b1, Wd, bd, bn1_g, bn1_b, bn1_m, bn1_v, W2, Pk);
  k_concat<<<(B * SV + 255) / 256, 256, 0, stream>>>(pep, mhc, X0);
  k_conv<<<B, 256, 0, stream>>>(X0, Pk, b2, ln_g, ln_b, X1);
  k_attn<<<B * H, 64, 0, stream>>>(X1, Wq, Wk, Wv, O);
  k_wo<<<B, 128, 0, stream>>>(O, Wo, X1, ln_g, ln_b, X2);
  dim3 g5(B / BT, NH / NT);
  k_f1<<<g5, 256, 0, stream>>>(X2, Wf1, bf1, bn2_g, bn2_b, bn2_m, bn2_v, Hb);
  k_f23<<<B, 64, 0, stream>>>(Hb, Wf2, bf2, Wf3, bf3, out);
}

// Round 4
// 1071.924 us; speedup vs baseline: 1.8727x; 1.1349x over previous
//
#include <hip/hip_runtime.h>
#include <hip/hip_bf16.h>

namespace {

constexpr int B   = 1024;
constexpr int PEP = 15;
constexpr int MHCN = 44;
constexpr int S   = 59;    // sequence
constexpr int V   = 21;    // vocab / model dim
constexpr int C   = 3200;  // conv channels
constexpr int KW  = 9;     // depthwise kernel
constexpr int H   = 9;     // heads
constexpr int NH  = 800;
constexpr int SV  = S * V;   // 1239
constexpr int HD  = H * V;   // 189
constexpr float EPSF = 1e-5f;

__device__ __forceinline__ float sigm(float x) { return 1.f / (1.f + __expf(-x)); }

// ---------------- K1: concat pep+mhc -> X0 [B,59,21] ----------------
__global__ void k_concat(const float* __restrict__ pep, const float* __restrict__ mhc,
                         float* __restrict__ X0) {
  int i = blockIdx.x * 256 + threadIdx.x;
  if (i >= B * SV) return;
  int b = i / SV;
  int r = i - b * SV;
  int l = r / V;
  int v = r - l * V;
  X0[i] = (l < PEP) ? pep[(b * PEP + l) * V + v] : mhc[(b * MHCN + (l - PEP)) * V + v];
}

// ---------------- K0: pack per-channel conv-module params ----------------
// Per-channel record (stride 88 floats = 352B, 16B aligned):
//   [0..20]  wa = W1[c]          [24..44] wg = W1[c+C]
//   [48..56] wd[9]   [57] ba  [58] bg  [59] sc2  [60] sh2
//   [64..84] w2t = W2[:, c]
constexpr int PKS = 88;
__global__ void k_pack(const float* __restrict__ W1, const float* __restrict__ b1,
                       const float* __restrict__ Wd, const float* __restrict__ bd,
                       const float* __restrict__ g, const float* __restrict__ bb,
                       const float* __restrict__ m, const float* __restrict__ vv,
                       const float* __restrict__ W2, float* __restrict__ pk) {
  int c = blockIdx.x * 64 + threadIdx.x;
  if (c >= C) return;
  float* p = pk + (size_t)c * PKS;
  for (int i = 0; i < V; ++i) p[i] = W1[c * V + i];
  for (int i = 0; i < V; ++i) p[24 + i] = W1[(c + C) * V + i];
  for (int k = 0; k < KW; ++k) p[48 + k] = Wd[c * KW + k];
  float sc = g[c] * rsqrtf(vv[c] + EPSF);
  p[57] = b1[c];
  p[58] = b1[c + C];
  p[59] = sc;
  p[60] = (bd[c] - m[c]) * sc + bb[c];
  for (int i = 0; i < V; ++i) p[64 + i] = W2[(size_t)i * C + c];
}

// ---------------- K2: fused conv module + residual + LN -> X1 ----------------
// One block per batch element, 8 waves (1024 blocks x 8 = 32 waves/CU -> full
// occupancy; R2's 4-wave version was grid-limited to 50%). lane = sequence
// position, wave-uniform channel; weights arrive as scalar loads. NO unroll
// pragma on the channel loop (cross-lane LDS RAW hazard with unrolling - R3
// failure). Deterministic two-stage cross-wave reduction (no atomics).
__global__ __launch_bounds__(512) void k_conv(
    const float* __restrict__ X0, const float* __restrict__ pack,
    const float* __restrict__ b2, const float* __restrict__ lng,
    const float* __restrict__ lnb, float* __restrict__ X1) {
  __shared__ float grow[8][72];      // per-wave depthwise exchange row (4-zero halo each side)
  __shared__ float part[4][64 * V];  // paired-wave down-proj partials
  __shared__ float yfull[SV];        // reduced down-proj output
  const int t = threadIdx.x;
  const int b = blockIdx.x;
  const int lane = t & 63;
  const int w = __builtin_amdgcn_readfirstlane(t >> 6);

  for (int i = t; i < 8 * 72; i += 512) (&grow[0][0])[i] = 0.f;

  // persistent registers: input row + down-proj accumulator
  float x[V];
  {
    const int row = lane < S ? lane : S - 1;
    const float* xr = X0 + (size_t)b * SV + row * V;
#pragma unroll
    for (int v = 0; v < V; ++v) x[v] = xr[v];
  }
  float yac[V];
#pragma unroll
  for (int v = 0; v < V; ++v) yac[v] = 0.f;
  __syncthreads();

  const bool wr = lane < S;
  for (int i = 0; i < C / 8; ++i) {
    const int c = 8 * i + w;  // wave-uniform channel
    const float* p = pack + (size_t)c * PKS;
    // ---- GLU ----
    float a = p[57], g = p[58];
#pragma unroll
    for (int v = 0; v < V; ++v) a = fmaf(x[v], p[v], a);
#pragma unroll
    for (int v = 0; v < V; ++v) g = fmaf(x[v], p[24 + v], g);
    const float gl = a * sigm(g);
    if (wr) grow[w][4 + lane] = gl;  // wave-synchronous: same wave consumes below
    // ---- depthwise conv + BN + SiLU ----
    float acc = 0.f;
#pragma unroll
    for (int k = 0; k < KW; ++k) acc = fmaf(grow[w][lane + k], p[48 + k], acc);
    acc = fmaf(acc, p[59], p[60]);
    const float sbv = acc * sigm(acc);
    // ---- down-projection accumulate (registers) ----
#pragma unroll
    for (int v = 0; v < V; ++v) yac[v] = fmaf(sbv, p[64 + v], yac[v]);
  }

  // deterministic two-stage cross-wave reduction
  if (w >= 4) {
#pragma unroll
    for (int v = 0; v < V; ++v) part[w - 4][lane * V + v] = yac[v];
  }
  __syncthreads();
  if (w < 4) {
#pragma unroll
    for (int v = 0; v < V; ++v) part[w][lane * V + v] += yac[v];
  }
  __syncthreads();
  for (int e = t; e < SV; e += 512)
    yfull[e] = (part[0][e] + part[1][e]) + (part[2][e] + part[3][e]);
  __syncthreads();

  // residual + b2 + LayerNorm over V (wave 0; x[] regs still hold the residual row)
  if (t < S) {
    float z[V];
    float mn = 0.f;
#pragma unroll
    for (int v = 0; v < V; ++v) {
      z[v] = x[v] + yfull[t * V + v] + b2[v];
      mn += z[v];
    }
    mn *= (1.f / V);
    float var = 0.f;
#pragma unroll
    for (int v = 0; v < V; ++v) {
      float d = z[v] - mn;
      var = fmaf(d, d, var);
    }
    const float inv = rsqrtf(var * (1.f / V) + EPSF);
#pragma unroll
    for (int v = 0; v < V; ++v)
      X1[(size_t)b * SV + t * V + v] = (z[v] - mn) * inv * lng[v] + lnb[v];
  }
}

// ---------------- K3: per-(b,h) attention, qkv fused -> O [B,59,189] ----------------
__global__ __launch_bounds__(64) void k_attn(
    const float* __restrict__ X1, const float* __restrict__ Wq, const float* __restrict__ Wk,
    const float* __restrict__ Wv, float* __restrict__ O) {
  __shared__ float Xs[SV], qs[SV], ks[SV], vs[SV];
  __shared__ float wqs[V * V], wks[V * V], wvs[V * V];
  __shared__ float ss[S * 61];  // score rows, odd stride
  const int t = threadIdx.x;
  const int bh = blockIdx.x;
  const int b = bh / H;
  const int h = bh - b * H;

  for (int i = t; i < SV; i += 64) Xs[i] = X1[b * SV + i];
  for (int i = t; i < V * V; i += 64) {
    int vv = i / V, d = i - vv * V;
    wqs[i] = Wq[vv * HD + h * V + d];
    wks[i] = Wk[vv * HD + h * V + d];
    wvs[i] = Wv[vv * HD + h * V + d];
  }
  __syncthreads();
  for (int i = t; i < SV; i += 64) {
    int l = i / V, d = i - l * V;
    float q = 0, k = 0, vv = 0;
#pragma unroll
    for (int u = 0; u < V; ++u) {
      float x = Xs[l * V + u];
      q  = fmaf(x, wqs[u * V + d], q);
      k  = fmaf(x, wks[u * V + d], k);
      vv = fmaf(x, wvs[u * V + d], vv);
    }
    qs[i] = q; ks[i] = k; vs[i] = vv;
  }
  __syncthreads();
  if (t < S) {
    const float rs = 0.21821789023599236f;  // 1/sqrt(21)
    float qr[V];
#pragma unroll
    for (int d = 0; d < V; ++d) qr[d] = qs[t * V + d];
    float mx = -1e30f;
    for (int j = 0; j < S; ++j) {
      float acc = 0;
#pragma unroll
      for (int d = 0; d < V; ++d) acc = fmaf(qr[d], ks[j * V + d], acc);
      acc *= rs;
      ss[t * 61 + j] = acc;
      mx = fmaxf(mx, acc);
    }
    float sum = 0;
    for (int j = 0; j < S; ++j) {
      float e = __expf(ss[t * 61 + j] - mx);
      ss[t * 61 + j] = e;
      sum += e;
    }
    const float inv = 1.f / sum;
    float o[V];
#pragma unroll
    for (int d = 0; d < V; ++d) o[d] = 0.f;
    for (int j = 0; j < S; ++j) {
      float p = ss[t * 61 + j];
#pragma unroll
      for (int d = 0; d < V; ++d) o[d] = fmaf(p, vs[j * V + d], o[d]);
    }
    float* op = O + (size_t)(b * S + t) * HD + h * V;
#pragma unroll
    for (int d = 0; d < V; ++d) op[d] = o[d] * inv;
  }
}

// ---------------- K4: O @ Wo + residual + LN -> X2 ----------------
__global__ __launch_bounds__(128) void k_wo(
    const float* __restrict__ O, const float* __restrict__ Wo, const float* __restrict__ X1,
    const float* __restrict__ lng, const float* __restrict__ lnb, float* __restrict__ X2) {
  __shared__ float Ws[HD * V];
  __shared__ float yo[SV];
  const int t = threadIdx.x;
  const int b = blockIdx.x;
  for (int i = t; i < HD * V; i += 128) Ws[i] = Wo[i];
  __syncthreads();
  for (int i = t; i < SV; i += 128) {
    int l = i / V, v = i - l * V;
    const float* orow = O + (size_t)(b * S + l) * HD;
    float acc = 0;
#pragma unroll 9
    for (int m = 0; m < HD; ++m) acc = fmaf(orow[m], Ws[m * V + v], acc);
    yo[i] = acc;
  }
  __syncthreads();
  if (t < S) {
    float z[V];
    float m = 0;
#pragma unroll
    for (int v = 0; v < V; ++v) {
      z[v] = X1[b * SV + t * V + v] + yo[t * V + v];
      m += z[v];
    }
    m *= (1.f / V);
    float var = 0;
#pragma unroll
    for (int v = 0; v < V; ++v) {
      float d = z[v] - m;
      var = fmaf(d, d, var);
    }
    const float inv = rsqrtf(var * (1.f / V) + EPSF);
#pragma unroll
    for (int v = 0; v < V; ++v)
      X2[b * SV + t * V + v] = (z[v] - m) * inv * lng[v] + lnb[v];
  }
}

// ---------------- K5: head GEMM [B,1239]@[1239,800] + bias + silu + BN -> Hb ----------------
constexpr int BT = 8;    // batch rows per block
constexpr int NT = 200;  // output cols per block
__global__ __launch_bounds__(256) void k_f1(
    const float* __restrict__ X2, const float* __restrict__ Wf1, const float* __restrict__ bf1,
    const float* __restrict__ g2, const float* __restrict__ bb2, const float* __restrict__ m2,
    const float* __restrict__ v2, float* __restrict__ Hb) {
  __shared__ __align__(16) float Xs[BT * 1240];
  const int t = threadIdx.x;
  const int bbase = blockIdx.x * BT;
  const int nbase = blockIdx.y * NT;
  for (int i = t; i < BT * SV; i += 256) {
    int r = i / SV, f = i - r * SV;
    Xs[r * 1240 + f] = X2[(size_t)(bbase + r) * SV + f];
  }
  __syncthreads();
  if (t < NT) {
    const int n = nbase + t;
    float acc[BT];
#pragma unroll
    for (int r = 0; r < BT; ++r) acc[r] = 0.f;
    int f = 0;
    for (; f + 3 < SV; f += 4) {
      const float w0 = Wf1[(size_t)f * NH + n];
      const float w1 = Wf1[(size_t)(f + 1) * NH + n];
      const float w2 = Wf1[(size_t)(f + 2) * NH + n];
      const float w3 = Wf1[(size_t)(f + 3) * NH + n];
#pragma unroll
      for (int r = 0; r < BT; ++r) {
        const float4 x = *reinterpret_cast<const float4*>(&Xs[r * 1240 + f]);
        acc[r] = fmaf(x.x, w0, acc[r]);
        acc[r] = fmaf(x.y, w1, acc[r]);
        acc[r] = fmaf(x.z, w2, acc[r]);
        acc[r] = fmaf(x.w, w3, acc[r]);
      }
    }
    for (; f < SV; ++f) {
      const float w0 = Wf1[(size_t)f * NH + n];
#pragma unroll
      for (int r = 0; r < BT; ++r) acc[r] = fmaf(Xs[r * 1240 + f], w0, acc[r]);
    }
    const float sc = g2[n] * rsqrtf(v2[n] + EPSF);
    const float sh = bb2[n] - m2[n] * sc;
    const float bias = bf1[n];
#pragma unroll
    for (int r = 0; r < BT; ++r) {
      float hh = acc[r] + bias;
      hh = hh * sigm(hh);            // silu
      hh = fmaf(hh, sc, sh);         // BN2 (inference)
      Hb[(size_t)(bbase + r) * NH + n] = hh;
    }
  }
}

// ---------------- K6: relu(Hb@Wf2+bf2) @ Wf3 + bf3 -> out [B,2] ----------------
__global__ __launch_bounds__(64) void k_f23(
    const float* __restrict__ Hb, const float* __restrict__ Wf2, const float* __restrict__ bf2,
    const float* __restrict__ Wf3, const float* __restrict__ bf3, float* __restrict__ out) {
  __shared__ __align__(16) float hs[NH];
  const int t = threadIdx.x;
  const int b = blockIdx.x;
  for (int i = t; i < NH; i += 64) hs[i] = Hb[(size_t)b * NH + i];
  __syncthreads();
  float acc = bf2[t];
  for (int n = 0; n < NH; n += 4) {
    const float4 hv = *reinterpret_cast<const float4*>(&hs[n]);
    acc = fmaf(hv.x, Wf2[n * 64 + t], acc);
    acc = fmaf(hv.y, Wf2[(n + 1) * 64 + t], acc);
    acc = fmaf(hv.z, Wf2[(n + 2) * 64 + t], acc);
    acc = fmaf(hv.w, Wf2[(n + 3) * 64 + t], acc);
  }
  const float mid = fmaxf(acc, 0.f);
  float p0 = mid * Wf3[t * 2 + 0];
  float p1 = mid * Wf3[t * 2 + 1];
#pragma unroll
  for (int off = 32; off > 0; off >>= 1) {
    p0 += __shfl_down(p0, off);
    p1 += __shfl_down(p1, off);
  }
  if (t == 0) {
    out[b * 2 + 0] = p0 + bf3[0];
    out[b * 2 + 1] = p1 + bf3[1];
  }
}

}  // namespace

extern "C" void kernel_launch(void* const* d_in, const int* in_sizes, int n_in,
                              void* d_out, int out_size, void* d_ws, size_t ws_size,
                              hipStream_t stream) {
  const float* pep   = (const float*)d_in[0];
  const float* mhc   = (const float*)d_in[1];
  const float* W1    = (const float*)d_in[2];
  const float* b1    = (const float*)d_in[3];
  const float* Wd    = (const float*)d_in[4];
  const float* bd    = (const float*)d_in[5];
  const float* bn1_g = (const float*)d_in[6];
  const float* bn1_b = (const float*)d_in[7];
  const float* bn1_m = (const float*)d_in[8];
  const float* bn1_v = (const float*)d_in[9];
  const float* W2    = (const float*)d_in[10];
  const float* b2    = (const float*)d_in[11];
  const float* ln_g  = (const float*)d_in[12];
  const float* ln_b  = (const float*)d_in[13];
  const float* Wq    = (const float*)d_in[14];
  const float* Wk    = (const float*)d_in[15];
  const float* Wv    = (const float*)d_in[16];
  const float* Wo    = (const float*)d_in[17];
  const float* Wf1   = (const float*)d_in[18];
  const float* bf1   = (const float*)d_in[19];
  const float* bn2_g = (const float*)d_in[20];
  const float* bn2_b = (const float*)d_in[21];
  const float* bn2_m = (const float*)d_in[22];
  const float* bn2_v = (const float*)d_in[23];
  const float* Wf2   = (const float*)d_in[24];
  const float* bf2   = (const float*)d_in[25];
  const float* Wf3   = (const float*)d_in[26];
  const float* bf3   = (const float*)d_in[27];
  float* out = (float*)d_out;

  float* ws = (float*)d_ws;
  float* X0 = ws;                          // [B,59,21]
  float* X1 = X0 + (size_t)B * SV;         // [B,59,21]
  float* X2 = X1 + (size_t)B * SV;         // [B,59,21]
  float* O  = X2 + (size_t)B * SV;         // [B,59,189]
  float* Hb = O + (size_t)B * S * HD;      // [B,800]
  float* Pk = Hb + (size_t)B * NH;         // [C,88] packed conv params

  k_pack<<<(C + 63) / 64, 64, 0, stream>>>(W1, b1, Wd, bd, bn1_g, bn1_b, bn1_m, bn1_v, W2, Pk);
  k_concat<<<(B * SV + 255) / 256, 256, 0, stream>>>(pep, mhc, X0);
  k_conv<<<B, 512, 0, stream>>>(X0, Pk, b2, ln_g, ln_b, X1);
  k_attn<<<B * H, 64, 0, stream>>>(X1, Wq, Wk, Wv, O);
  k_wo<<<B, 128, 0, stream>>>(O, Wo, X1, ln_g, ln_b, X2);
  dim3 g5(B / BT, NH / NT);
  k_f1<<<g5, 256, 0, stream>>>(X2, Wf1, bf1, bn2_g, bn2_b, bn2_m, bn2_v, Hb);
  k_f23<<<B, 64, 0, stream>>>(Hb, Wf2, bf2, Wf3, bf3, out);
}

// Round 5
// 930.854 us; speedup vs baseline: 2.1565x; 1.1515x over previous
//
#include <hip/hip_runtime.h>
#include <hip/hip_bf16.h>

namespace {

constexpr int B   = 1024;
constexpr int PEP = 15;
constexpr int MHCN = 44;
constexpr int S   = 59;    // sequence
constexpr int V   = 21;    // vocab / model dim
constexpr int C   = 3200;  // conv channels
constexpr int KW  = 9;     // depthwise kernel
constexpr int H   = 9;     // heads
constexpr int NH  = 800;
constexpr int SV  = S * V;   // 1239
constexpr int HD  = H * V;   // 189
constexpr float EPSF = 1e-5f;

__device__ __forceinline__ float sigm(float x) { return 1.f / (1.f + __expf(-x)); }

// ---------------- K0: pack per-channel conv-module params ----------------
// Per-channel record (stride 88 floats = 352B, 16B aligned):
//   [0..20]  wa = W1[c]          [24..44] wg = W1[c+C]
//   [48..56] wd[9]   [57] ba  [58] bg  [59] sc2  [60] sh2
//   [64..84] w2t = W2[:, c]
constexpr int PKS = 88;
__global__ void k_pack(const float* __restrict__ W1, const float* __restrict__ b1,
                       const float* __restrict__ Wd, const float* __restrict__ bd,
                       const float* __restrict__ g, const float* __restrict__ bb,
                       const float* __restrict__ m, const float* __restrict__ vv,
                       const float* __restrict__ W2, float* __restrict__ pk) {
  int c = blockIdx.x * 64 + threadIdx.x;
  if (c >= C) return;
  float* p = pk + (size_t)c * PKS;
  for (int i = 0; i < V; ++i) p[i] = W1[c * V + i];
  for (int i = 0; i < V; ++i) p[24 + i] = W1[(c + C) * V + i];
  for (int k = 0; k < KW; ++k) p[48 + k] = Wd[c * KW + k];
  float sc = g[c] * rsqrtf(vv[c] + EPSF);
  p[57] = b1[c];
  p[58] = b1[c + C];
  p[59] = sc;
  p[60] = (bd[c] - m[c]) * sc + bb[c];
  for (int i = 0; i < V; ++i) p[64 + i] = W2[(size_t)i * C + c];
}

// ---------------- K2: fused concat + conv module + residual + LN -> X1 ----------------
// One block per batch element, 8 waves. lane = sequence position, wave-uniform
// channel; weights arrive as scalar loads. __launch_bounds__(512,4): cap at 4
// waves/EU -> 128 VGPR budget so x[21]+yac[21] stay in arch VGPRs (R4 ran at
// VGPR_Count=28 -> accvgpr shuffling consumed ~half the VALU cycles).
// NO unroll pragma on the channel loop (cross-lane LDS RAW hazard - R3 failure).
__global__ __launch_bounds__(512, 4) void k_conv(
    const float* __restrict__ pep, const float* __restrict__ mhc,
    const float* __restrict__ pack,
    const float* __restrict__ b2, const float* __restrict__ lng,
    const float* __restrict__ lnb, float* __restrict__ X1) {
  __shared__ float grow[8][72];      // per-wave depthwise exchange row (4-zero halo each side)
  __shared__ float part[4][64 * V];  // paired-wave down-proj partials
  __shared__ float yfull[SV];        // reduced down-proj output
  const int t = threadIdx.x;
  const int b = blockIdx.x;
  const int lane = t & 63;
  const int w = __builtin_amdgcn_readfirstlane(t >> 6);

  for (int i = t; i < 8 * 72; i += 512) (&grow[0][0])[i] = 0.f;

  // persistent registers: input row (concat of pep/mhc) + down-proj accumulator
  const int row = lane < S ? lane : S - 1;
  const float* xr = (row < PEP) ? pep + ((size_t)b * PEP + row) * V
                                : mhc + ((size_t)b * MHCN + (row - PEP)) * V;
  float x[V];
#pragma unroll
  for (int v = 0; v < V; ++v) x[v] = xr[v];
  float yac[V];
#pragma unroll
  for (int v = 0; v < V; ++v) yac[v] = 0.f;
  __syncthreads();

  const bool wr = lane < S;
  for (int i = 0; i < C / 8; ++i) {
    const int c = 8 * i + w;  // wave-uniform channel
    const float* p = pack + (size_t)c * PKS;
    // ---- GLU ----
    float a = p[57], g = p[58];
#pragma unroll
    for (int v = 0; v < V; ++v) a = fmaf(x[v], p[v], a);
#pragma unroll
    for (int v = 0; v < V; ++v) g = fmaf(x[v], p[24 + v], g);
    const float gl = a * sigm(g);
    if (wr) grow[w][4 + lane] = gl;  // wave-synchronous: same wave consumes below
    // ---- depthwise conv + BN + SiLU ----
    float acc = 0.f;
#pragma unroll
    for (int k = 0; k < KW; ++k) acc = fmaf(grow[w][lane + k], p[48 + k], acc);
    acc = fmaf(acc, p[59], p[60]);
    const float sbv = acc * sigm(acc);
    // ---- down-projection accumulate (registers) ----
#pragma unroll
    for (int v = 0; v < V; ++v) yac[v] = fmaf(sbv, p[64 + v], yac[v]);
  }

  // deterministic two-stage cross-wave reduction
  if (w >= 4) {
#pragma unroll
    for (int v = 0; v < V; ++v) part[w - 4][lane * V + v] = yac[v];
  }
  __syncthreads();
  if (w < 4) {
#pragma unroll
    for (int v = 0; v < V; ++v) part[w][lane * V + v] += yac[v];
  }
  __syncthreads();
  for (int e = t; e < SV; e += 512)
    yfull[e] = (part[0][e] + part[1][e]) + (part[2][e] + part[3][e]);
  __syncthreads();

  // residual + b2 + LayerNorm over V (wave 0; x[] regs still hold the residual row)
  if (t < S) {
    float z[V];
    float mn = 0.f;
#pragma unroll
    for (int v = 0; v < V; ++v) {
      z[v] = x[v] + yfull[t * V + v] + b2[v];
      mn += z[v];
    }
    mn *= (1.f / V);
    float var = 0.f;
#pragma unroll
    for (int v = 0; v < V; ++v) {
      float d = z[v] - mn;
      var = fmaf(d, d, var);
    }
    const float inv = rsqrtf(var * (1.f / V) + EPSF);
#pragma unroll
    for (int v = 0; v < V; ++v)
      X1[(size_t)b * SV + t * V + v] = (z[v] - mn) * inv * lng[v] + lnb[v];
  }
}

// ---------------- K3: per-(b,h) attention -> O [B,59,189] ----------------
// lane = row. x row + q row in registers; QKV weights read as wave-uniform
// s_loads straight from global (never staged); only k/v rows + score rows in
// LDS. Lanes 59..63 duplicate row 58 (identical values -> benign LDS dup write).
__global__ __launch_bounds__(64, 4) void k_attn(
    const float* __restrict__ X1, const float* __restrict__ Wq, const float* __restrict__ Wk,
    const float* __restrict__ Wv, float* __restrict__ O) {
  __shared__ float ks[SV], vs[SV];
  __shared__ float ss[S * 61];  // score rows, odd stride
  const int lane = threadIdx.x;
  const int bh = blockIdx.x;
  const int b = bh / H;
  const int h = bh - b * H;
  const int row = lane < S ? lane : S - 1;

  float x[V];
  {
    const float* xr = X1 + (size_t)b * SV + row * V;
#pragma unroll
    for (int u = 0; u < V; ++u) x[u] = xr[u];
  }
  const float* wqh = Wq + h * V;
  const float* wkh = Wk + h * V;
  const float* wvh = Wv + h * V;
  float q[V];
  for (int d = 0; d < V; ++d) {
    float qa = 0.f, ka = 0.f, va = 0.f;
#pragma unroll
    for (int u = 0; u < V; ++u) {
      const float xv = x[u];
      qa = fmaf(xv, wqh[u * HD + d], qa);  // weight addr wave-uniform -> s_load
      ka = fmaf(xv, wkh[u * HD + d], ka);
      va = fmaf(xv, wvh[u * HD + d], va);
    }
    q[d] = qa;
    ks[row * V + d] = ka;   // lanes 59-63 rewrite row 58 with identical values
    vs[row * V + d] = va;
  }
  __syncthreads();

  if (lane < S) {
    const float rs = 0.21821789023599236f;  // 1/sqrt(21)
    float mx = -1e30f;
    for (int j = 0; j < S; ++j) {
      float acc = 0.f;
#pragma unroll
      for (int d = 0; d < V; ++d) acc = fmaf(q[d], ks[j * V + d], acc);
      acc *= rs;
      ss[lane * 61 + j] = acc;
      mx = fmaxf(mx, acc);
    }
    float sum = 0.f;
    for (int j = 0; j < S; ++j) {
      float e = __expf(ss[lane * 61 + j] - mx);
      ss[lane * 61 + j] = e;
      sum += e;
    }
    const float inv = 1.f / sum;
    float o[V];
#pragma unroll
    for (int d = 0; d < V; ++d) o[d] = 0.f;
    for (int j = 0; j < S; ++j) {
      const float p = ss[lane * 61 + j];
#pragma unroll
      for (int d = 0; d < V; ++d) o[d] = fmaf(p, vs[j * V + d], o[d]);
    }
    float* op = O + (size_t)(b * S + lane) * HD + h * V;
#pragma unroll
    for (int d = 0; d < V; ++d) op[d] = o[d] * inv;
  }
}

// ---------------- K4: O @ Wo + residual + LN -> X2 ----------------
__global__ __launch_bounds__(128) void k_wo(
    const float* __restrict__ O, const float* __restrict__ Wo, const float* __restrict__ X1,
    const float* __restrict__ lng, const float* __restrict__ lnb, float* __restrict__ X2) {
  __shared__ float Ws[HD * V];
  __shared__ float yo[SV];
  const int t = threadIdx.x;
  const int b = blockIdx.x;
  for (int i = t; i < HD * V; i += 128) Ws[i] = Wo[i];
  __syncthreads();
  for (int i = t; i < SV; i += 128) {
    int l = i / V, v = i - l * V;
    const float* orow = O + (size_t)(b * S + l) * HD;
    float acc = 0;
#pragma unroll 9
    for (int m = 0; m < HD; ++m) acc = fmaf(orow[m], Ws[m * V + v], acc);
    yo[i] = acc;
  }
  __syncthreads();
  if (t < S) {
    float z[V];
    float m = 0;
#pragma unroll
    for (int v = 0; v < V; ++v) {
      z[v] = X1[b * SV + t * V + v] + yo[t * V + v];
      m += z[v];
    }
    m *= (1.f / V);
    float var = 0;
#pragma unroll
    for (int v = 0; v < V; ++v) {
      float d = z[v] - m;
      var = fmaf(d, d, var);
    }
    const float inv = rsqrtf(var * (1.f / V) + EPSF);
#pragma unroll
    for (int v = 0; v < V; ++v)
      X2[b * SV + t * V + v] = (z[v] - m) * inv * lng[v] + lnb[v];
  }
}

// ---------------- K5: head GEMM [B,1239]@[1239,800] + bias + silu + BN -> Hb ----------------
constexpr int BT = 8;    // batch rows per block
constexpr int NT = 200;  // output cols per block
__global__ __launch_bounds__(256) void k_f1(
    const float* __restrict__ X2, const float* __restrict__ Wf1, const float* __restrict__ bf1,
    const float* __restrict__ g2, const float* __restrict__ bb2, const float* __restrict__ m2,
    const float* __restrict__ v2, float* __restrict__ Hb) {
  __shared__ __align__(16) float Xs[BT * 1240];
  const int t = threadIdx.x;
  const int bbase = blockIdx.x * BT;
  const int nbase = blockIdx.y * NT;
  for (int i = t; i < BT * SV; i += 256) {
    int r = i / SV, f = i - r * SV;
    Xs[r * 1240 + f] = X2[(size_t)(bbase + r) * SV + f];
  }
  __syncthreads();
  if (t < NT) {
    const int n = nbase + t;
    float acc[BT];
#pragma unroll
    for (int r = 0; r < BT; ++r) acc[r] = 0.f;
    int f = 0;
    for (; f + 3 < SV; f += 4) {
      const float w0 = Wf1[(size_t)f * NH + n];
      const float w1 = Wf1[(size_t)(f + 1) * NH + n];
      const float w2 = Wf1[(size_t)(f + 2) * NH + n];
      const float w3 = Wf1[(size_t)(f + 3) * NH + n];
#pragma unroll
      for (int r = 0; r < BT; ++r) {
        const float4 x = *reinterpret_cast<const float4*>(&Xs[r * 1240 + f]);
        acc[r] = fmaf(x.x, w0, acc[r]);
        acc[r] = fmaf(x.y, w1, acc[r]);
        acc[r] = fmaf(x.z, w2, acc[r]);
        acc[r] = fmaf(x.w, w3, acc[r]);
      }
    }
    for (; f < SV; ++f) {
      const float w0 = Wf1[(size_t)f * NH + n];
#pragma unroll
      for (int r = 0; r < BT; ++r) acc[r] = fmaf(Xs[r * 1240 + f], w0, acc[r]);
    }
    const float sc = g2[n] * rsqrtf(v2[n] + EPSF);
    const float sh = bb2[n] - m2[n] * sc;
    const float bias = bf1[n];
#pragma unroll
    for (int r = 0; r < BT; ++r) {
      float hh = acc[r] + bias;
      hh = hh * sigm(hh);            // silu
      hh = fmaf(hh, sc, sh);         // BN2 (inference)
      Hb[(size_t)(bbase + r) * NH + n] = hh;
    }
  }
}

// ---------------- K6: relu(Hb@Wf2+bf2) @ Wf3 + bf3 -> out [B,2] ----------------
__global__ __launch_bounds__(64) void k_f23(
    const float* __restrict__ Hb, const float* __restrict__ Wf2, const float* __restrict__ bf2,
    const float* __restrict__ Wf3, const float* __restrict__ bf3, float* __restrict__ out) {
  __shared__ __align__(16) float hs[NH];
  const int t = threadIdx.x;
  const int b = blockIdx.x;
  for (int i = t; i < NH; i += 64) hs[i] = Hb[(size_t)b * NH + i];
  __syncthreads();
  float acc = bf2[t];
  for (int n = 0; n < NH; n += 4) {
    const float4 hv = *reinterpret_cast<const float4*>(&hs[n]);
    acc = fmaf(hv.x, Wf2[n * 64 + t], acc);
    acc = fmaf(hv.y, Wf2[(n + 1) * 64 + t], acc);
    acc = fmaf(hv.z, Wf2[(n + 2) * 64 + t], acc);
    acc = fmaf(hv.w, Wf2[(n + 3) * 64 + t], acc);
  }
  const float mid = fmaxf(acc, 0.f);
  float p0 = mid * Wf3[t * 2 + 0];
  float p1 = mid * Wf3[t * 2 + 1];
#pragma unroll
  for (int off = 32; off > 0; off >>= 1) {
    p0 += __shfl_down(p0, off);
    p1 += __shfl_down(p1, off);
  }
  if (t == 0) {
    out[b * 2 + 0] = p0 + bf3[0];
    out[b * 2 + 1] = p1 + bf3[1];
  }
}

}  // namespace

extern "C" void kernel_launch(void* const* d_in, const int* in_sizes, int n_in,
                              void* d_out, int out_size, void* d_ws, size_t ws_size,
                              hipStream_t stream) {
  const float* pep   = (const float*)d_in[0];
  const float* mhc   = (const float*)d_in[1];
  const float* W1    = (const float*)d_in[2];
  const float* b1    = (const float*)d_in[3];
  const float* Wd    = (const float*)d_in[4];
  const float* bd    = (const float*)d_in[5];
  const float* bn1_g = (const float*)d_in[6];
  const float* bn1_b = (const float*)d_in[7];
  const float* bn1_m = (const float*)d_in[8];
  const float* bn1_v = (const float*)d_in[9];
  const float* W2    = (const float*)d_in[10];
  const float* b2    = (const float*)d_in[11];
  const float* ln_g  = (const float*)d_in[12];
  const float* ln_b  = (const float*)d_in[13];
  const float* Wq    = (const float*)d_in[14];
  const float* Wk    = (const float*)d_in[15];
  const float* Wv    = (const float*)d_in[16];
  const float* Wo    = (const float*)d_in[17];
  const float* Wf1   = (const float*)d_in[18];
  const float* bf1   = (const float*)d_in[19];
  const float* bn2_g = (const float*)d_in[20];
  const float* bn2_b = (const float*)d_in[21];
  const float* bn2_m = (const float*)d_in[22];
  const float* bn2_v = (const float*)d_in[23];
  const float* Wf2   = (const float*)d_in[24];
  const float* bf2   = (const float*)d_in[25];
  const float* Wf3   = (const float*)d_in[26];
  const float* bf3   = (const float*)d_in[27];
  float* out = (float*)d_out;

  float* ws = (float*)d_ws;
  float* X1 = ws;                          // [B,59,21]
  float* X2 = X1 + (size_t)B * SV;         // [B,59,21]
  float* O  = X2 + (size_t)B * SV;         // [B,59,189]
  float* Hb = O + (size_t)B * S * HD;      // [B,800]
  float* Pk = Hb + (size_t)B * NH;         // [C,88] packed conv params

  k_pack<<<(C + 63) / 64, 64, 0, stream>>>(W1, b1, Wd, bd, bn1_g, bn1_b, bn1_m, bn1_v, W2, Pk);
  k_conv<<<B, 512, 0, stream>>>(pep, mhc, Pk, b2, ln_g, ln_b, X1);
  k_attn<<<B * H, 64, 0, stream>>>(X1, Wq, Wk, Wv, O);
  k_wo<<<B, 128, 0, stream>>>(O, Wo, X1, ln_g, ln_b, X2);
  dim3 g5(B / BT, NH / NT);
  k_f1<<<g5, 256, 0, stream>>>(X2, Wf1, bf1, bn2_g, bn2_b, bn2_m, bn2_v, Hb);
  k_f23<<<B, 64, 0, stream>>>(Hb, Wf2, bf2, Wf3, bf3, out);
}